// Round 5
// baseline (260.547 us; speedup 1.0000x reference)
//
#include <hip/hip_runtime.h>

// GraphSAGE layer, fp32, N=50000, E=800000, 64->64.
// R5: partitioned CSR (8 edge-range partitions, XCD-affine work stealing,
// disjoint col regions -> no cross-XCD line bouncing) + single fused
// gather/normalize/dual-GEMM/ReLU kernel (wave per node, weights in VGPRs,
// readlane broadcasts -> no transpose, no LDS tile, no agg buffer).

#define N_NODES 50000
#define N_EDGES 800000
#define DIM 64
#define NPART 8
#define E_PER (N_EDGES / NPART)            // 100000 edges per partition
#define PAD 50176                          // 49*1024 >= N_NODES
#define NCHUNK 49                          // scan chunks per partition
#define COLPAD 100352                      // per-partition col region (>= E_PER)
#define CHK 512                            // edges per steal chunk
#define NSTEAL ((E_PER + CHK - 1) / CHK)   // 196

__device__ __forceinline__ int get_xcd() {
    unsigned int x;
    asm volatile("s_getreg_b32 %0, hwreg(HW_REG_XCC_ID)" : "=s"(x));
    return (int)(x & 7);
}

// ---------------------------------------------------------------------------
// 1) per-partition histogram. Wave-level work stealing; partition p's chunks
//    are normally processed by XCD p (its cnt lines stay in ONE L2); fallback
//    probing of other partitions guarantees coverage for any block placement.
// ---------------------------------------------------------------------------
__global__ __launch_bounds__(256) void sage_hist8(const int* __restrict__ src,
                                                  int* __restrict__ cnt8,
                                                  int* __restrict__ hctr)
{
    int p0 = get_xcd();
    int lane = threadIdx.x & 63;
    for (int pp = 0; pp < NPART; ++pp) {
        int p = (p0 + pp) & 7;
        const int* s = src + p * E_PER;
        int* cp = cnt8 + p * PAD;
        for (;;) {
            int c;
            if (lane == 0) c = atomicAdd(&hctr[p * 64], 1);
            c = __shfl(c, 0);
            if (c >= NSTEAL) break;
            int base = c * CHK + lane;
#pragma unroll
            for (int i = 0; i < CHK / 64; ++i) {
                int el = base + i * 64;
                if (el < E_PER) atomicAdd(&cp[s[el]], 1);
            }
        }
    }
}

// ---------------------------------------------------------------------------
// 2a) per-1024-chunk sums (8 partitions * 49 chunks = 392 blocks)
// ---------------------------------------------------------------------------
__global__ __launch_bounds__(256) void scan_reduce(const int* __restrict__ cnt8,
                                                   int* __restrict__ partial)
{
    __shared__ int sdata[256];
    int t = threadIdx.x, b = blockIdx.x;
    const int4 c = *reinterpret_cast<const int4*>(cnt8 + b * 1024 + t * 4);
    sdata[t] = c.x + c.y + c.z + c.w;
    __syncthreads();
    for (int st = 128; st > 0; st >>= 1) {
        if (t < st) sdata[t] += sdata[t + st];
        __syncthreads();
    }
    if (t == 0) partial[b] = sdata[0];
}

// 2b) 8 independent exclusive scans of 49 chunk sums (wave per partition)
__global__ void scan_partials(int* partial)
{
    int w = threadIdx.x >> 6;             // partition
    int lane = threadIdx.x & 63;
    int idx = w * NCHUNK + lane;
    int orig = (lane < NCHUNK) ? partial[idx] : 0;
    int v = orig;
#pragma unroll
    for (int off = 1; off < 64; off <<= 1) {
        int u = __shfl_up(v, off);
        if (lane >= off) v += u;
    }
    if (lane < NCHUNK) partial[idx] = v - orig;
}

// 2c) within-chunk exclusive scan + chunk prefix -> per-partition offsets
//     (written twice: offsp for the reader, cursorp for the filler)
// ---------------------------------------------------------------------------
__global__ __launch_bounds__(256) void scan_write(const int* __restrict__ cnt8,
                                                  const int* __restrict__ partial,
                                                  int* __restrict__ offsp,
                                                  int* __restrict__ cursorp)
{
    int t = threadIdx.x, b = blockIdx.x;
    int base = b * 1024 + t * 4;
    const int4 c = *reinterpret_cast<const int4*>(cnt8 + base);
    int tsum = c.x + c.y + c.z + c.w;
    int lane = t & 63, w = t >> 6;
    int v = tsum;
#pragma unroll
    for (int off = 1; off < 64; off <<= 1) {
        int u = __shfl_up(v, off);
        if (lane >= off) v += u;
    }
    __shared__ int wsum[4];
    if (lane == 63) wsum[w] = v;
    __syncthreads();
    int woff = 0;
    for (int k = 0; k < w; ++k) woff += wsum[k];
    int excl = partial[b] + woff + (v - tsum);
    int4 o; o.x = excl; o.y = o.x + c.x; o.z = o.y + c.y; o.w = o.z + c.z;
    *reinterpret_cast<int4*>(offsp + base) = o;
    *reinterpret_cast<int4*>(cursorp + base) = o;
}

// ---------------------------------------------------------------------------
// 3) partitioned CSR fill: same stealing scheme; partition p's cursor lines
//    and col region are touched (normally) only by XCD p.
// ---------------------------------------------------------------------------
__global__ __launch_bounds__(256) void sage_fill8(const int* __restrict__ src,
                                                  const int* __restrict__ dst,
                                                  int* __restrict__ cursorp,
                                                  int* __restrict__ col,
                                                  int* __restrict__ fctr)
{
    int p0 = get_xcd();
    int lane = threadIdx.x & 63;
    for (int pp = 0; pp < NPART; ++pp) {
        int p = (p0 + pp) & 7;
        const int* s = src + p * E_PER;
        const int* d = dst + p * E_PER;
        int* cur = cursorp + p * PAD;
        int* cl = col + p * COLPAD;
        for (;;) {
            int c;
            if (lane == 0) c = atomicAdd(&fctr[p * 64], 1);
            c = __shfl(c, 0);
            if (c >= NSTEAL) break;
            int base = c * CHK + lane;
#pragma unroll
            for (int i = 0; i < CHK / 64; ++i) {
                int el = base + i * 64;
                if (el < E_PER) {
                    int sv = s[el];
                    int pos = atomicAdd(&cur[sv], 1);
                    cl[pos] = d[el];
                }
            }
        }
    }
}

// ---------------------------------------------------------------------------
// 4) fused gather-mean + dual GEMM + bias + ReLU. One wave per node (4
//    nodes/wave sequentially). lane = feature dim for the gather (coalesced
//    256B row loads), lane = output dim for the GEMM. Per-lane weight rows
//    Ws[lane][*], Wn[lane][*] live in 128 VGPRs (staged via pad-68 LDS:
//    bank-group (lane+c)&7 -> conflict-free ds_read_b128). x[k]/agg[k]
//    broadcast via v_readlane (SGPR operand of v_fma).
// ---------------------------------------------------------------------------
__global__ __launch_bounds__(256, 1) void sage_fused(
    const float* __restrict__ x,
    const int* __restrict__ col,
    const int* __restrict__ offsp,
    const int* __restrict__ cnt8,
    const float* __restrict__ Ws,
    const float* __restrict__ bs,
    const float* __restrict__ Wn,
    const float* __restrict__ bn,
    float* __restrict__ out)
{
    __shared__ float wl[2][DIM * 68];
    const int t = threadIdx.x;
#pragma unroll
    for (int i = 0; i < 16; ++i) {
        int idx = t + i * 256;           // 0..4095
        int o = idx >> 6, k = idx & 63;
        wl[0][o * 68 + k] = Ws[idx];
        wl[1][o * 68 + k] = Wn[idx];
    }
    __syncthreads();

    const int lane = t & 63;
    float ws[DIM], wn[DIM];
#pragma unroll
    for (int c = 0; c < 16; ++c) {
        float4 a = *reinterpret_cast<const float4*>(&wl[0][lane * 68 + c * 4]);
        ws[c * 4 + 0] = a.x; ws[c * 4 + 1] = a.y;
        ws[c * 4 + 2] = a.z; ws[c * 4 + 3] = a.w;
        float4 b = *reinterpret_cast<const float4*>(&wl[1][lane * 68 + c * 4]);
        wn[c * 4 + 0] = b.x; wn[c * 4 + 1] = b.y;
        wn[c * 4 + 2] = b.z; wn[c * 4 + 3] = b.w;
    }

    const float bias = bs[lane] + bn[lane];
    const int nb = blockIdx.x * 16 + (t >> 6) * 4;

#pragma unroll 1
    for (int j = 0; j < 4; ++j) {
        const int n = __builtin_amdgcn_readfirstlane(nb + j);
        float xv = x[n * DIM + lane];
        float aggv = 0.0f;
        int deg = 0;
#pragma unroll
        for (int p = 0; p < NPART; ++p) {
            int beg = __builtin_amdgcn_readfirstlane(offsp[p * PAD + n]);
            int cnt = __builtin_amdgcn_readfirstlane(cnt8[p * PAD + n]);
            deg += cnt;
            const int* cptr = col + p * COLPAD + beg;
            int i = 0;
            for (; i + 2 <= cnt; i += 2) {
                int d0 = __builtin_amdgcn_readfirstlane(cptr[i]);
                int d1 = __builtin_amdgcn_readfirstlane(cptr[i + 1]);
                aggv += x[d0 * DIM + lane];
                aggv += x[d1 * DIM + lane];
            }
            if (i < cnt) {
                int d = __builtin_amdgcn_readfirstlane(cptr[i]);
                aggv += x[d * DIM + lane];
            }
        }
        aggv *= 1.0f / (float)(deg > 0 ? deg : 1);

        float acc = bias;
        int xi = __float_as_int(xv);
        int ai = __float_as_int(aggv);
#pragma unroll
        for (int k = 0; k < DIM; ++k) {
            float sx = __int_as_float(__builtin_amdgcn_readlane(xi, k));
            float sa = __int_as_float(__builtin_amdgcn_readlane(ai, k));
            acc = fmaf(sx, ws[k], acc);
            acc = fmaf(sa, wn[k], acc);
        }
        out[n * DIM + lane] = fmaxf(acc, 0.0f);
    }
}

extern "C" void kernel_launch(void* const* d_in, const int* in_sizes, int n_in,
                              void* d_out, int out_size, void* d_ws, size_t ws_size,
                              hipStream_t stream)
{
    const float* x      = (const float*)d_in[0];
    const int*   ei     = (const int*)d_in[1];   // [2,E]: row 0 = src, row 1 = dst
    const float* Wself  = (const float*)d_in[2];
    const float* bself  = (const float*)d_in[3];
    const float* Wneigh = (const float*)d_in[4];
    const float* bneigh = (const float*)d_in[5];
    float* out = (float*)d_out;

    // workspace layout (int units)
    int* cnt8    = (int*)d_ws;                 // 8*PAD = 401408
    int* hctr    = cnt8 + NPART * PAD;         // 512 (8 counters, 256B apart)
    int* fctr    = hctr + 512;                 // 512
    int* partial = fctr + 512;                 // 512 (392 used)
    int* offsp   = partial + 512;              // 8*PAD
    int* cursorp = offsp + NPART * PAD;        // 8*PAD
    int* col     = cursorp + NPART * PAD;      // 8*COLPAD = 802816

    const int* src = ei;
    const int* dst = ei + N_EDGES;

    hipMemsetAsync(cnt8, 0, (size_t)(NPART * PAD + 1024) * sizeof(int), stream);

    sage_hist8   <<<1024, 256, 0, stream>>>(src, cnt8, hctr);
    scan_reduce  <<<NPART * NCHUNK, 256, 0, stream>>>(cnt8, partial);
    scan_partials<<<1, 512, 0, stream>>>(partial);
    scan_write   <<<NPART * NCHUNK, 256, 0, stream>>>(cnt8, partial, offsp, cursorp);
    sage_fill8   <<<1024, 256, 0, stream>>>(src, dst, cursorp, col, fctr);

    sage_fused   <<<N_NODES / 16, 256, 0, stream>>>(x, col, offsp, cnt8,
                                                    Wself, bself, Wneigh, bneigh, out);
}

// Round 6
// 185.992 us; speedup vs baseline: 1.4008x; 1.4008x over previous
//
#include <hip/hip_runtime.h>

// GraphSAGE layer, fp32, N=50000 nodes, E=800000 edges, 64->64.
// R6 = R3 pipeline (hist -> scan -> fill -> agg) + rebuilt sage_out:
// LDS-broadcast GEMM, weight rows in VGPRs, coalesced staging.

#define N_NODES 50000
#define N_EDGES 800000
#define DIM 64
#define NB_SCAN 49            // 49 blocks * 1024 = 50176 >= N_NODES
#define CNT_PAD (NB_SCAN * 1024)

// ---------------------------------------------------------------------------
// 1) degree histogram (int atomics)
// ---------------------------------------------------------------------------
__global__ __launch_bounds__(256) void sage_hist(const int* __restrict__ src,
                                                 int* __restrict__ cnt)
{
    int e = blockIdx.x * 256 + threadIdx.x;
    if (e < N_EDGES) atomicAdd(&cnt[src[e]], 1);
}

// ---------------------------------------------------------------------------
// 2a) per-1024-chunk reduction
// ---------------------------------------------------------------------------
__global__ __launch_bounds__(256) void scan_reduce(const int* __restrict__ cnt,
                                                   int* __restrict__ partial)
{
    __shared__ int sdata[256];
    int t = threadIdx.x, b = blockIdx.x;
    int s = 0;
#pragma unroll
    for (int i = 0; i < 4; ++i) s += cnt[b * 1024 + i * 256 + t];
    sdata[t] = s; __syncthreads();
    for (int st = 128; st > 0; st >>= 1) {
        if (t < st) sdata[t] += sdata[t + st];
        __syncthreads();
    }
    if (t == 0) partial[b] = sdata[0];
}

// 2b) exclusive scan of the 49 chunk sums (single wave)
__global__ void scan_partials(int* partial)
{
    int t = threadIdx.x;
    int orig = (t < NB_SCAN) ? partial[t] : 0;
    int v = orig;
#pragma unroll
    for (int off = 1; off < 64; off <<= 1) {
        int u = __shfl_up(v, off);
        if (t >= off) v += u;
    }
    if (t < NB_SCAN) partial[t] = v - orig;
}

// 2c) per-chunk exclusive scan + chunk prefix -> row offsets + cursor copy
__global__ __launch_bounds__(256) void scan_write(const int* __restrict__ cnt,
                                                  const int* __restrict__ partial,
                                                  int* __restrict__ offs,
                                                  int* __restrict__ cursor)
{
    int t = threadIdx.x, b = blockIdx.x;
    int base = b * 1024 + t * 4;
    const int4 c = *reinterpret_cast<const int4*>(cnt + base);
    int tsum = c.x + c.y + c.z + c.w;
    int lane = t & 63, w = t >> 6;
    int v = tsum;
#pragma unroll
    for (int off = 1; off < 64; off <<= 1) {
        int u = __shfl_up(v, off);
        if (lane >= off) v += u;
    }
    __shared__ int wsum[4];
    if (lane == 63) wsum[w] = v;
    __syncthreads();
    int woff = 0;
    for (int k = 0; k < w; ++k) woff += wsum[k];
    int excl = partial[b] + woff + (v - tsum);
    int4 o; o.x = excl; o.y = o.x + c.x; o.z = o.y + c.y; o.w = o.z + c.z;
    *reinterpret_cast<int4*>(offs + base) = o;
    *reinterpret_cast<int4*>(cursor + base) = o;
}

// ---------------------------------------------------------------------------
// 3) CSR fill (R3 version — known 48 us; attacked next round)
// ---------------------------------------------------------------------------
__global__ __launch_bounds__(256) void sage_fill(const int* __restrict__ src,
                                                 const int* __restrict__ dst,
                                                 int* __restrict__ cursor,
                                                 int* __restrict__ col)
{
    int e = blockIdx.x * 256 + threadIdx.x;
    if (e < N_EDGES) {
        int s = src[e];
        int pos = atomicAdd(&cursor[s], 1);
        col[pos] = dst[e];
    }
}

// ---------------------------------------------------------------------------
// 4) gather-mean (R3 version): one wave per node, readfirstlane col batches,
//    8 independent row-gathers in flight.
// ---------------------------------------------------------------------------
__global__ __launch_bounds__(256) void sage_agg(const float* __restrict__ x,
                                                const int* __restrict__ col,
                                                const int* __restrict__ offs,
                                                float* __restrict__ agg)
{
    int wid = (blockIdx.x * 256 + threadIdx.x) >> 6;
    int lane = threadIdx.x & 63;
    if (wid >= N_NODES) return;
    int beg = __builtin_amdgcn_readfirstlane(offs[wid]);
    int end = __builtin_amdgcn_readfirstlane(offs[wid + 1]);
    float s = 0.0f;
    int i = beg;
    for (; i + 8 <= end; i += 8) {
        int d0 = __builtin_amdgcn_readfirstlane(col[i + 0]);
        int d1 = __builtin_amdgcn_readfirstlane(col[i + 1]);
        int d2 = __builtin_amdgcn_readfirstlane(col[i + 2]);
        int d3 = __builtin_amdgcn_readfirstlane(col[i + 3]);
        int d4 = __builtin_amdgcn_readfirstlane(col[i + 4]);
        int d5 = __builtin_amdgcn_readfirstlane(col[i + 5]);
        int d6 = __builtin_amdgcn_readfirstlane(col[i + 6]);
        int d7 = __builtin_amdgcn_readfirstlane(col[i + 7]);
        float t0 = x[d0 * DIM + lane] + x[d1 * DIM + lane];
        float t1 = x[d2 * DIM + lane] + x[d3 * DIM + lane];
        float t2 = x[d4 * DIM + lane] + x[d5 * DIM + lane];
        float t3 = x[d6 * DIM + lane] + x[d7 * DIM + lane];
        s += (t0 + t1) + (t2 + t3);
    }
    for (; i < end; ++i) {
        int d = __builtin_amdgcn_readfirstlane(col[i]);
        s += x[d * DIM + lane];
    }
    int deg = end - beg;
    float inv = 1.0f / (float)(deg > 0 ? deg : 1);
    agg[(size_t)wid * DIM + lane] = s * inv;
}

// ---------------------------------------------------------------------------
// 5) fused dual GEMM + bias + relu, rebuilt.
//    Block = 256 threads (4 waves) / 16 nodes.
//    - x/agg rows staged to LDS with perfectly coalesced float4 loads
//      (16 consecutive node rows are 4KB contiguous in memory).
//    - lane = output dim. Lane holds weight rows Ws[lane][*], Wn[lane][*]
//      in 128 VGPRs (one-time load; L1 absorbs the strided pattern since
//      the 16 b128 loads per matrix walk consecutive 16B of each line).
//    - inner loop: wave-uniform ds_read_b128 broadcast of x[k..k+3] /
//      agg[k..k+3] (same addr all lanes -> conflict-free) + 8 FMAs.
//    - out write: lane-contiguous 256B per wave.
// ---------------------------------------------------------------------------
__global__ __launch_bounds__(256, 3) void sage_out(const float* __restrict__ x,
                                                   const float* __restrict__ agg,
                                                   const float* __restrict__ Ws,
                                                   const float* __restrict__ bs,
                                                   const float* __restrict__ Wn,
                                                   const float* __restrict__ bn,
                                                   float* __restrict__ out)
{
    __shared__ float xs[16][DIM];
    __shared__ float as[16][DIM];
    const int t = threadIdx.x;
    const int lane = t & 63;
    const int w = t >> 6;
    const int nbase = blockIdx.x * 16;     // grid sized exactly: 3125*16=50000

    // coalesced staging: 256 float4 per array
    const float4* __restrict__ x4 = reinterpret_cast<const float4*>(x) + (size_t)nbase * 16;
    const float4* __restrict__ a4 = reinterpret_cast<const float4*>(agg) + (size_t)nbase * 16;
    reinterpret_cast<float4*>(&xs[0][0])[t] = x4[t];
    reinterpret_cast<float4*>(&as[0][0])[t] = a4[t];

    // weight rows into VGPRs (static indexing only -> registers)
    float ws[DIM], wn[DIM];
    {
        const float4* __restrict__ W4 = reinterpret_cast<const float4*>(Ws) + lane * 16;
        const float4* __restrict__ N4 = reinterpret_cast<const float4*>(Wn) + lane * 16;
#pragma unroll
        for (int c = 0; c < 16; ++c) {
            float4 a = W4[c];
            ws[c * 4 + 0] = a.x; ws[c * 4 + 1] = a.y;
            ws[c * 4 + 2] = a.z; ws[c * 4 + 3] = a.w;
            float4 b = N4[c];
            wn[c * 4 + 0] = b.x; wn[c * 4 + 1] = b.y;
            wn[c * 4 + 2] = b.z; wn[c * 4 + 3] = b.w;
        }
    }
    const float bias = bs[lane] + bn[lane];
    __syncthreads();

#pragma unroll
    for (int jj = 0; jj < 4; ++jj) {
        const int j = w * 4 + jj;          // wave-uniform node index in tile
        float acc = bias;
#pragma unroll
        for (int kc = 0; kc < 16; ++kc) {
            float4 xv = *reinterpret_cast<const float4*>(&xs[j][kc * 4]);
            float4 av = *reinterpret_cast<const float4*>(&as[j][kc * 4]);
            acc = fmaf(xv.x, ws[kc * 4 + 0], acc);
            acc = fmaf(xv.y, ws[kc * 4 + 1], acc);
            acc = fmaf(xv.z, ws[kc * 4 + 2], acc);
            acc = fmaf(xv.w, ws[kc * 4 + 3], acc);
            acc = fmaf(av.x, wn[kc * 4 + 0], acc);
            acc = fmaf(av.y, wn[kc * 4 + 1], acc);
            acc = fmaf(av.z, wn[kc * 4 + 2], acc);
            acc = fmaf(av.w, wn[kc * 4 + 3], acc);
        }
        out[(size_t)(nbase + j) * DIM + lane] = fmaxf(acc, 0.0f);
    }
}

extern "C" void kernel_launch(void* const* d_in, const int* in_sizes, int n_in,
                              void* d_out, int out_size, void* d_ws, size_t ws_size,
                              hipStream_t stream)
{
    const float* x      = (const float*)d_in[0];
    const int*   ei     = (const int*)d_in[1];   // [2,E]: row 0 = src, row 1 = dst
    const float* Wself  = (const float*)d_in[2];
    const float* bself  = (const float*)d_in[3];
    const float* Wneigh = (const float*)d_in[4];
    const float* bneigh = (const float*)d_in[5];
    float* out = (float*)d_out;

    // workspace layout (4-byte units)
    float* agg   = (float*)d_ws;                        // 3,200,000
    int* col     = (int*)(agg + (size_t)N_NODES * DIM); // 800,000
    int* cnt     = col + N_EDGES;                       // CNT_PAD
    int* offs    = cnt + CNT_PAD;                       // CNT_PAD
    int* cursor  = offs + CNT_PAD;                      // CNT_PAD
    int* partial = cursor + CNT_PAD;                    // 64

    const int* src = ei;
    const int* dst = ei + N_EDGES;

    hipMemsetAsync(cnt, 0, CNT_PAD * sizeof(int), stream);

    sage_hist    <<<(N_EDGES + 255) / 256, 256, 0, stream>>>(src, cnt);
    scan_reduce  <<<NB_SCAN, 256, 0, stream>>>(cnt, partial);
    scan_partials<<<1, 64, 0, stream>>>(partial);
    scan_write   <<<NB_SCAN, 256, 0, stream>>>(cnt, partial, offs, cursor);
    sage_fill    <<<(N_EDGES + 255) / 256, 256, 0, stream>>>(src, dst, cursor, col);

    sage_agg <<<N_NODES / 4, 256, 0, stream>>>(x, col, offs, agg);   // 50000 waves
    sage_out <<<N_NODES / 16, 256, 0, stream>>>(x, agg, Wself, bself,
                                                Wneigh, bneigh, out);
}